// Round 1
// baseline (599.872 us; speedup 1.0000x reference)
//
#include <hip/hip_runtime.h>

#define NN 100000
#define NE 1600000
#define FIN 256
#define FHID 128
#define FCLS 64

typedef _Float16 f16;
typedef __attribute__((ext_vector_type(8))) _Float16 f16x8;
typedef __attribute__((ext_vector_type(2))) _Float16 f16x2;
typedef __attribute__((ext_vector_type(4))) float f32x4;

// ---------------- degree / norm ----------------
__global__ __launch_bounds__(256) void k_deg(const int* __restrict__ src, const int* __restrict__ dst,
                                             int* __restrict__ outdeg, int* __restrict__ indeg) {
  int e = blockIdx.x * 256 + threadIdx.x;
  if (e < NE) {
    atomicAdd(&outdeg[src[e]], 1);
    atomicAdd(&indeg[dst[e]], 1);
  }
}

__global__ __launch_bounds__(256) void k_norm(const int* __restrict__ outdeg, const int* __restrict__ indeg,
                                              float* __restrict__ onorm, float* __restrict__ inorm) {
  int i = blockIdx.x * 256 + threadIdx.x;
  if (i < NN) {
    int od = outdeg[i]; if (od < 1) od = 1;
    int id = indeg[i]; if (id < 1) id = 1;
    onorm[i] = rsqrtf((float)od);
    inorm[i] = rsqrtf((float)id);
  }
}

// ---------------- CSR build: hierarchical exclusive scan + fill ----------------
__global__ __launch_bounds__(256) void k_scan_a(const int* __restrict__ indeg, int* __restrict__ rp,
                                                int* __restrict__ bsum) {
  __shared__ int sm[256];
  int t = threadIdx.x;
  int i = blockIdx.x * 256 + t;
  int v = (i < NN) ? indeg[i] : 0;
  int x = v;
  sm[t] = x;
  __syncthreads();
  for (int off = 1; off < 256; off <<= 1) {
    int y = (t >= off) ? sm[t - off] : 0;
    __syncthreads();
    x += y;
    sm[t] = x;
    __syncthreads();
  }
  if (i < NN) rp[i] = x - v;           // exclusive within block
  if (t == 255) bsum[blockIdx.x] = x;  // block total
}

__global__ __launch_bounds__(512) void k_scan_b(int* __restrict__ bsum, int nb) {
  __shared__ int sm[512];
  int t = threadIdx.x;
  int v = (t < nb) ? bsum[t] : 0;
  int x = v;
  sm[t] = x;
  __syncthreads();
  for (int off = 1; off < 512; off <<= 1) {
    int y = (t >= off) ? sm[t - off] : 0;
    __syncthreads();
    x += y;
    sm[t] = x;
    __syncthreads();
  }
  bsum[t] = x - v;  // exclusive block offsets
}

__global__ __launch_bounds__(256) void k_scan_c(int* __restrict__ rp, const int* __restrict__ bsum,
                                                int* __restrict__ cursor) {
  int i = blockIdx.x * 256 + threadIdx.x;
  if (i < NN) {
    int r = rp[i] + bsum[blockIdx.x];
    rp[i] = r;
    cursor[i] = r;
  }
  if (i == 0) rp[NN] = NE;
}

__global__ __launch_bounds__(256) void k_fill(const int* __restrict__ src, const int* __restrict__ dst,
                                              int* __restrict__ cursor, int* __restrict__ csr) {
  int e = blockIdx.x * 256 + threadIdx.x;
  if (e < NE) {
    int ppos = atomicAdd(&cursor[dst[e]], 1);
    csr[ppos] = src[e];
  }
}

// ---------------- weight pack: fragment-major f16 for mfma 16x16x32 ----------------
// B fragment: lane l needs B[k][n] with n = t*16 + (l&15), k = s*32 + (l>>4)*8 + i
template <int K, int NW>
__global__ __launch_bounds__(256) void k_packw(const float* __restrict__ W, f16* __restrict__ Wp) {
  int idx = blockIdx.x * 256 + threadIdx.x;
  if (idx >= K * NW) return;
  constexpr int nT = NW / 16;
  int i = idx & 7;
  int l = (idx >> 3) & 63;
  int rest = idx >> 9;
  int t = rest % nT;
  int s = rest / nT;
  int k = s * 32 + (l >> 4) * 8 + i;
  int n = t * 16 + (l & 15);
  Wp[idx] = (f16)W[k * NW + n];
}

// ---------------- GEMM: [M=NN x K] @ [K x NW] via mfma_f32_16x16x32_f16 ----------------
// MODE 0: A = f32 x, rows scaled by onorm[row]; store f16 plain.        (layer 1 transform)
// MODE 1: A = f16; store f16 plain.                                      (layer 3 transform)
// MODE 2: A = f16; store f16 relu(acc + bias[col]) * onorm[row].        (layer 2 transform)
template <int K, int NW, int MODE>
__global__ __launch_bounds__(256) void k_gemm(const void* __restrict__ Asrc, const f16* __restrict__ Wp,
                                              const float* __restrict__ onorm, const float* __restrict__ bias,
                                              f16* __restrict__ Out) {
  constexpr int nS = K / 32, nT = NW / 16;
  int lane = threadIdx.x & 63;
  int w = threadIdx.x >> 6;
  int bm = blockIdx.x * 64 + w * 16;  // this wave's 16-row tile
  int arow = bm + (lane & 15);
  int koff = (lane >> 4) * 8;
  bool rowok = arow < NN;

  f32x4 acc[nT];
#pragma unroll
  for (int t = 0; t < nT; ++t) acc[t] = (f32x4){0.f, 0.f, 0.f, 0.f};

  float ascale = 0.0f;
  if (MODE == 0) ascale = rowok ? onorm[arow] : 0.0f;

  for (int s = 0; s < nS; ++s) {
    f16x8 a = {};
    if (rowok) {
      if (MODE == 0) {
        const float* ap = (const float*)Asrc + (size_t)arow * K + s * 32 + koff;
        f32x4 v0 = *(const f32x4*)ap;
        f32x4 v1 = *(const f32x4*)(ap + 4);
#pragma unroll
        for (int j = 0; j < 4; ++j) {
          a[j] = (f16)(v0[j] * ascale);
          a[4 + j] = (f16)(v1[j] * ascale);
        }
      } else {
        a = *(const f16x8*)((const f16*)Asrc + (size_t)arow * K + s * 32 + koff);
      }
    }
    const f16* bp = Wp + ((size_t)(s * nT) * 64 + lane) * 8;
#pragma unroll
    for (int t = 0; t < nT; ++t) {
      f16x8 b = *(const f16x8*)(bp + t * 512);
      acc[t] = __builtin_amdgcn_mfma_f32_16x16x32_f16(a, b, acc[t], 0, 0, 0);
    }
  }

  // C/D layout: col = lane&15, row = (lane>>4)*4 + reg
  int crow0 = bm + (lane >> 4) * 4;
  int ccol = lane & 15;
#pragma unroll
  for (int t = 0; t < nT; ++t) {
#pragma unroll
    for (int r = 0; r < 4; ++r) {
      int row = crow0 + r;
      if (row >= NN) continue;
      int col = t * 16 + ccol;
      float v = acc[t][r];
      if (MODE == 2) v = fmaxf(v + bias[col], 0.f) * onorm[row];
      Out[(size_t)row * NW + col] = (f16)v;
    }
  }
}

// ---------------- aggregation: per-node gather-sum over CSR in-edges ----------------
// MODE 0: out f16 = relu(acc*inorm + bias[f]) * onorm[node]   (after layer-1 agg)
// MODE 1: out f16 = acc*inorm                                  (pre-layer-2 GEMM, in_norm folded)
// MODE 2: out f32 = acc*inorm + bias[f]                        (final output)
template <int W, int MODE>
__global__ __launch_bounds__(256) void k_agg(const f16* __restrict__ src_arr, const int* __restrict__ rp,
                                             const int* __restrict__ csr, const float* __restrict__ inorm,
                                             const float* __restrict__ onorm, const float* __restrict__ bias,
                                             void* __restrict__ outp) {
  constexpr int LPN = W / 2;  // lanes per node, 2 features/lane
  int tid = blockIdx.x * 256 + threadIdx.x;
  int node = tid / LPN;
  int fo = (tid % LPN) * 2;
  if (node >= NN) return;
  int beg = rp[node], end = rp[node + 1];
  float a0 = 0.f, a1 = 0.f;
  int e = beg;
  for (; e + 1 < end; e += 2) {  // 2x unroll for MLP
    int s0 = csr[e], s1 = csr[e + 1];
    f16x2 v0 = *(const f16x2*)(src_arr + (size_t)s0 * W + fo);
    f16x2 v1 = *(const f16x2*)(src_arr + (size_t)s1 * W + fo);
    a0 += (float)v0[0] + (float)v1[0];
    a1 += (float)v0[1] + (float)v1[1];
  }
  if (e < end) {
    int s0 = csr[e];
    f16x2 v0 = *(const f16x2*)(src_arr + (size_t)s0 * W + fo);
    a0 += (float)v0[0];
    a1 += (float)v0[1];
  }
  float inn = inorm[node];
  if (MODE == 0) {
    float on = onorm[node];
    f16x2 o;
    o[0] = (f16)(fmaxf(a0 * inn + bias[fo], 0.f) * on);
    o[1] = (f16)(fmaxf(a1 * inn + bias[fo + 1], 0.f) * on);
    *(f16x2*)((f16*)outp + (size_t)node * W + fo) = o;
  } else if (MODE == 1) {
    f16x2 o;
    o[0] = (f16)(a0 * inn);
    o[1] = (f16)(a1 * inn);
    *(f16x2*)((f16*)outp + (size_t)node * W + fo) = o;
  } else {
    float* op = (float*)outp + (size_t)node * W + fo;
    op[0] = a0 * inn + bias[fo];
    op[1] = a1 * inn + bias[fo + 1];
  }
}

extern "C" void kernel_launch(void* const* d_in, const int* in_sizes, int n_in,
                              void* d_out, int out_size, void* d_ws, size_t ws_size,
                              hipStream_t stream) {
  const float* x = (const float*)d_in[0];
  const int* src = (const int*)d_in[1];
  const int* dst = (const int*)d_in[2];
  const float* W1 = (const float*)d_in[3];
  const float* b1 = (const float*)d_in[4];
  const float* W2 = (const float*)d_in[5];
  const float* b2 = (const float*)d_in[6];
  const float* W3 = (const float*)d_in[7];
  const float* b3 = (const float*)d_in[8];

  char* base = (char*)d_ws;
  size_t off = 0;
  auto take = [&](size_t bytes) -> void* {
    void* r = base + off;
    off += (bytes + 255) & ~(size_t)255;
    return r;
  };
  int* outdeg = (int*)take((size_t)NN * 4);
  int* indeg = (int*)take((size_t)NN * 4);
  float* onorm = (float*)take((size_t)NN * 4);
  float* inorm = (float*)take((size_t)NN * 4);
  int* rp = (int*)take((size_t)(NN + 1) * 4);
  int* cursor = (int*)take((size_t)NN * 4);
  int* bsum = (int*)take(512 * 4);
  int* csr = (int*)take((size_t)NE * 4);
  f16* W1p = (f16*)take((size_t)FIN * FHID * 2);
  f16* W2p = (f16*)take((size_t)FHID * FHID * 2);
  f16* W3p = (f16*)take((size_t)FHID * FCLS * 2);
  // two ping-pong feature buffers (aliased across stages)
  f16* B1 = (f16*)take((size_t)NN * FHID * 2);  // t1 -> agg2 -> t3
  f16* B2 = (f16*)take((size_t)NN * FHID * 2);  // g1 -> g2

  hipMemsetAsync(outdeg, 0, (size_t)NN * 4, stream);
  hipMemsetAsync(indeg, 0, (size_t)NN * 4, stream);

  int nb = (NN + 255) / 256;  // 391 <= 512
  k_deg<<<(NE + 255) / 256, 256, 0, stream>>>(src, dst, outdeg, indeg);
  k_norm<<<nb, 256, 0, stream>>>(outdeg, indeg, onorm, inorm);
  k_scan_a<<<nb, 256, 0, stream>>>(indeg, rp, bsum);
  k_scan_b<<<1, 512, 0, stream>>>(bsum, nb);
  k_scan_c<<<nb, 256, 0, stream>>>(rp, bsum, cursor);
  k_fill<<<(NE + 255) / 256, 256, 0, stream>>>(src, dst, cursor, csr);

  k_packw<FIN, FHID><<<(FIN * FHID + 255) / 256, 256, 0, stream>>>(W1, W1p);
  k_packw<FHID, FHID><<<(FHID * FHID + 255) / 256, 256, 0, stream>>>(W2, W2p);
  k_packw<FHID, FCLS><<<(FHID * FCLS + 255) / 256, 256, 0, stream>>>(W3, W3p);

  const int gemm_grid = (NN + 63) / 64;
  // layer 1: t1 = (x*onorm) @ W1
  k_gemm<FIN, FHID, 0><<<gemm_grid, 256, 0, stream>>>(x, W1p, onorm, nullptr, B1);
  // g1 = relu(agg(t1)*inorm + b1) * onorm
  k_agg<FHID, 0><<<(NN * (FHID / 2) + 255) / 256, 256, 0, stream>>>(B1, rp, csr, inorm, onorm, b1, B2);
  // layer 2: agg2 = agg(g1)*inorm  (in_norm folded before GEMM — linear)
  k_agg<FHID, 1><<<(NN * (FHID / 2) + 255) / 256, 256, 0, stream>>>(B2, rp, csr, inorm, nullptr, nullptr, B1);
  // g2 = relu(agg2 @ W2 + b2) * onorm
  k_gemm<FHID, FHID, 2><<<gemm_grid, 256, 0, stream>>>(B1, W2p, onorm, b2, B2);
  // layer 3: t3 = g2 @ W3
  k_gemm<FHID, FCLS, 1><<<gemm_grid, 256, 0, stream>>>(B2, W3p, nullptr, nullptr, B1);
  // out = agg(t3)*inorm + b3
  k_agg<FCLS, 2><<<(NN * (FCLS / 2) + 255) / 256, 256, 0, stream>>>(B1, rp, csr, inorm, nullptr, b3, d_out);
}